// Round 3
// baseline (432.174 us; speedup 1.0000x reference)
//
#include <hip/hip_runtime.h>
#include <math.h>

// ColumnBlockAttention: b=16, t=8192, e=64, BLOCK=64, n_cols=128
// d_out = [out: b*t*64 f32 | A: b*t*128 f32].
//
// Mapping: 1 wave per 16 rows of a (b, m) row-block. lane = 4*r + s:
// r = row-in-wave (0..15), s = 16-dim slice of the embedding (0..3).
// Per group of 4 columns: each lane does 16-dim partial dots for the 4 cols,
// quad butterfly (__shfl_xor 1,2) completes all 4 scores in all 4 lanes,
// 4 exps, then PV FMAs immediately (e stays in registers). One
// ds_write_b32/group saves e into a conflict-free E array (stride 132)
// for the A epilogue. No cross-wave communication; no barriers on hot path.

#define TSEQ 8192
#define EDIM 64
#define NCOL 128
#define NBATCH 16
#define EPAD 132   // 132 % 32 == 4 -> dot-phase writes land on bank = lane id

__global__ __launch_bounds__(64, 4)
void cba_kernel(const float* __restrict__ Q,
                const float* __restrict__ K,
                const float* __restrict__ V,
                float* __restrict__ Out,
                float* __restrict__ A)
{
    __shared__ float E[16 * EPAD];   // 8448 B: e[row-in-wave][col]

    const int lane = threadIdx.x;        // 0..63 (one wave per block)
    const int s    = lane & 3;           // dim slice
    const int rp   = lane >> 2;          // row within wave, 0..15

    const int blk = blockIdx.x;
    const int b   = blk >> 9;                  // batch 0..15
    const int m   = 127 - ((blk >> 2) & 127);  // row-block; big-m dispatched first
    const int w   = blk & 3;                   // which 16-row slice of the block

    const int rl  = (w << 4) + rp;             // row within 64-row block
    const int i   = (m << 6) + rl;             // global row
    const int nv  = m + (rl == 63);            // valid column count (causal)

    // ---- q slice, pre-scaled by 1/sqrt(64) ----
    const float4* qp = (const float4*)(Q + (size_t)(b * TSEQ + i) * EDIM + (s << 4));
    float4 q[4];
    #pragma unroll
    for (int t = 0; t < 4; ++t) {
        float4 v = qp[t];
        v.x *= 0.125f; v.y *= 0.125f; v.z *= 0.125f; v.w *= 0.125f;
        q[t] = v;
    }

    // column j lives at K/V row 64j+63; per-column float stride = 4096
    const float* kp = K + ((size_t)b * TSEQ + 63) * EDIM + (s << 4);
    const float* vp = V + ((size_t)b * TSEQ + 63) * EDIM + (s << 4);

    float lsum = 0.f;
    float4 o0 = make_float4(0,0,0,0), o1 = make_float4(0,0,0,0);
    float4 o2 = make_float4(0,0,0,0), o3 = make_float4(0,0,0,0);

    float* Erow = E + rp * EPAD;
    const int ng = (m >> 2) + 1;               // groups of 4 columns

    for (int u = 0; u < ng; ++u) {
        const float4* k0 = (const float4*)(kp);
        const float4* k1 = (const float4*)(kp + 4096);
        const float4* k2 = (const float4*)(kp + 8192);
        const float4* k3 = (const float4*)(kp + 12288);
        float4 ka[4], kb[4], kc[4], kd[4];
        #pragma unroll
        for (int t = 0; t < 4; ++t) { ka[t] = k0[t]; kb[t] = k1[t]; kc[t] = k2[t]; kd[t] = k3[t]; }

        float4 p0 = make_float4(0,0,0,0), p1 = make_float4(0,0,0,0);
        float4 p2 = make_float4(0,0,0,0), p3 = make_float4(0,0,0,0);
        #pragma unroll
        for (int t = 0; t < 4; ++t) {
            p0.x += q[t].x * ka[t].x; p0.y += q[t].y * ka[t].y; p0.z += q[t].z * ka[t].z; p0.w += q[t].w * ka[t].w;
            p1.x += q[t].x * kb[t].x; p1.y += q[t].y * kb[t].y; p1.z += q[t].z * kb[t].z; p1.w += q[t].w * kb[t].w;
            p2.x += q[t].x * kc[t].x; p2.y += q[t].y * kc[t].y; p2.z += q[t].z * kc[t].z; p2.w += q[t].w * kc[t].w;
            p3.x += q[t].x * kd[t].x; p3.y += q[t].y * kd[t].y; p3.z += q[t].z * kd[t].z; p3.w += q[t].w * kd[t].w;
        }
        float s0 = (p0.x + p0.y) + (p0.z + p0.w);
        float s1 = (p1.x + p1.y) + (p1.z + p1.w);
        float s2 = (p2.x + p2.y) + (p2.z + p2.w);
        float s3 = (p3.x + p3.y) + (p3.z + p3.w);
        // quad butterfly: all 4 lanes get all 4 full dots
        s0 += __shfl_xor(s0, 1); s0 += __shfl_xor(s0, 2);
        s1 += __shfl_xor(s1, 1); s1 += __shfl_xor(s1, 2);
        s2 += __shfl_xor(s2, 1); s2 += __shfl_xor(s2, 2);
        s3 += __shfl_xor(s3, 1); s3 += __shfl_xor(s3, 2);

        const int jb = u << 2;
        float e0 = (jb + 0 < nv) ? __expf(s0) : 0.f;
        float e1 = (jb + 1 < nv) ? __expf(s1) : 0.f;
        float e2 = (jb + 2 < nv) ? __expf(s2) : 0.f;
        float e3 = (jb + 3 < nv) ? __expf(s3) : 0.f;
        lsum += (e0 + e1) + (e2 + e3);

        // lane s records e for column jb+s (conflict-free: bank = lane id)
        float es = (s == 0) ? e0 : (s == 1) ? e1 : (s == 2) ? e2 : e3;
        Erow[jb + s] = es;

        // PV: accumulate this group's 4 columns into the o slice
        const float4* v0 = (const float4*)(vp);
        const float4* v1 = (const float4*)(vp + 4096);
        const float4* v2 = (const float4*)(vp + 8192);
        const float4* v3 = (const float4*)(vp + 12288);
        float4 va[4], vb_[4], vc[4], vd[4];
        #pragma unroll
        for (int t = 0; t < 4; ++t) { va[t] = v0[t]; vb_[t] = v1[t]; vc[t] = v2[t]; vd[t] = v3[t]; }
        o0.x += e0*va[0].x + e1*vb_[0].x + e2*vc[0].x + e3*vd[0].x;
        o0.y += e0*va[0].y + e1*vb_[0].y + e2*vc[0].y + e3*vd[0].y;
        o0.z += e0*va[0].z + e1*vb_[0].z + e2*vc[0].z + e3*vd[0].z;
        o0.w += e0*va[0].w + e1*vb_[0].w + e2*vc[0].w + e3*vd[0].w;
        o1.x += e0*va[1].x + e1*vb_[1].x + e2*vc[1].x + e3*vd[1].x;
        o1.y += e0*va[1].y + e1*vb_[1].y + e2*vc[1].y + e3*vd[1].y;
        o1.z += e0*va[1].z + e1*vb_[1].z + e2*vc[1].z + e3*vd[1].z;
        o1.w += e0*va[1].w + e1*vb_[1].w + e2*vc[1].w + e3*vd[1].w;
        o2.x += e0*va[2].x + e1*vb_[2].x + e2*vc[2].x + e3*vd[2].x;
        o2.y += e0*va[2].y + e1*vb_[2].y + e2*vc[2].y + e3*vd[2].y;
        o2.z += e0*va[2].z + e1*vb_[2].z + e2*vc[2].z + e3*vd[2].z;
        o2.w += e0*va[2].w + e1*vb_[2].w + e2*vc[2].w + e3*vd[2].w;
        o3.x += e0*va[3].x + e1*vb_[3].x + e2*vc[3].x + e3*vd[3].x;
        o3.y += e0*va[3].y + e1*vb_[3].y + e2*vc[3].y + e3*vd[3].y;
        o3.z += e0*va[3].z + e1*vb_[3].z + e2*vc[3].z + e3*vd[3].z;
        o3.w += e0*va[3].w + e1*vb_[3].w + e2*vc[3].w + e3*vd[3].w;

        kp += 16384; vp += 16384;   // advance 4 columns
    }

    const float rinv = (lsum > 0.f) ? 1.0f / lsum : 0.f;

    // ---- out: lane's 16-dim slice of its row ----
    float4* orow = (float4*)(Out + (size_t)(b * TSEQ + i) * EDIM + (s << 4));
    o0.x *= rinv; o0.y *= rinv; o0.z *= rinv; o0.w *= rinv;
    o1.x *= rinv; o1.y *= rinv; o1.z *= rinv; o1.w *= rinv;
    o2.x *= rinv; o2.y *= rinv; o2.z *= rinv; o2.w *= rinv;
    o3.x *= rinv; o3.y *= rinv; o3.z *= rinv; o3.w *= rinv;
    orow[0] = o0; orow[1] = o1; orow[2] = o2; orow[3] = o3;

    __syncthreads();   // single-wave block: cheap; orders quad E writes vs reads

    // ---- A: lane covers columns [32s, 32s+32) of its row ----
    float4* arow = (float4*)(A + (size_t)(b * TSEQ + i) * NCOL + (s << 5));
    #pragma unroll
    for (int kk = 0; kk < 8; ++kk) {
        const int c0 = (s << 5) + (kk << 2);
        float4 ev = *(const float4*)(Erow + c0);
        float4 av;
        av.x = (c0 + 0 < nv) ? ev.x * rinv : 0.f;
        av.y = (c0 + 1 < nv) ? ev.y * rinv : 0.f;
        av.z = (c0 + 2 < nv) ? ev.z * rinv : 0.f;
        av.w = (c0 + 3 < nv) ? ev.w * rinv : 0.f;
        arow[kk] = av;
    }
}

extern "C" void kernel_launch(void* const* d_in, const int* in_sizes, int n_in,
                              void* d_out, int out_size, void* d_ws, size_t ws_size,
                              hipStream_t stream) {
    const float* Q = (const float*)d_in[0];
    const float* K = (const float*)d_in[1];
    const float* V = (const float*)d_in[2];
    float* Out = (float*)d_out;
    float* A   = Out + (size_t)NBATCH * TSEQ * EDIM;

    // 8192 one-wave workgroups: 16 batches x 128 row-blocks x 4 row-slices
    cba_kernel<<<dim3(NBATCH * NCOL * 4), dim3(64), 0, stream>>>(Q, K, V, Out, A);
}

// Round 4
// 188.601 us; speedup vs baseline: 2.2915x; 2.2915x over previous
//
#include <hip/hip_runtime.h>
#include <math.h>

// ColumnBlockAttention via bf16 MFMA: b=16, t=8192, e=64, BLOCK=64, n_cols=128
// d_out = [out: b*t*64 f32 | A: b*t*128 f32].
//
// One workgroup (4 waves) per (batch b, row-block m):
//   GEMM1: Z(64x128) = Q(64x64) . Kc^T   (mfma_f32_16x16x32_bf16, f32 acc)
//   mask + exp + per-row shuffle reduce -> normalized weights -> LDS (bf16)
//   A written from LDS (coalesced f32), GEMM2: out(64x64) = Aw(64x128) . Vc
// Layouts (HW-verified m89/m120): A-frag A[m=lane&15][k=(lane>>4)*8+j],
// B-frag B[k][n]: n=lane&15, k=(lane>>4)*8+j; C/D col=lane&15,
// row=(lane>>4)*4+reg. Both LDS operands stored [m-or-n][k] so every
// fragment is one 16B-aligned ds_read_b128.

#define TSEQ 8192
#define EDIM 64
#define NCOL 128
#define NBATCH 16

typedef __attribute__((ext_vector_type(8))) short short8;
typedef __attribute__((ext_vector_type(4))) float f32x4;

__device__ __forceinline__ unsigned short f2bf(float f) {   // RTNE bf16
    unsigned int u = __float_as_uint(f);
    return (unsigned short)((u + 0x7fffu + ((u >> 16) & 1u)) >> 16);
}
__device__ __forceinline__ float bf2f(unsigned short h) {
    return __uint_as_float(((unsigned int)h) << 16);
}

__global__ __launch_bounds__(256, 3)
void cba_kernel(const float* __restrict__ Q,
                const float* __restrict__ K,
                const float* __restrict__ V,
                float* __restrict__ Out,
                float* __restrict__ A)
{
    __shared__ unsigned short Kc[NCOL][72];    // Kc[col][dim], pad 72
    __shared__ unsigned short VcT[EDIM][136];  // VcT[dim][col], pad 136
    __shared__ unsigned short Aw[64][136];     // weights [row][col], pad 136

    const int tid  = threadIdx.x;
    const int lane = tid & 63;
    const int wid  = tid >> 6;                 // 0..3: rows [16w,16w+16)
    const int b    = blockIdx.x >> 7;
    const int m    = blockIdx.x & 127;

    const size_t rowbase = (size_t)b * TSEQ + ((size_t)m << 6);

    // ---- stage Kc (bf16) and VcT (bf16, transposed) ----
    {
        const int j = tid >> 1;                // column 0..127
        const int h = (tid & 1) << 5;          // dim half: 0 or 32
        const size_t src = ((size_t)b * TSEQ + (j * 64 + 63)) * EDIM + h;
        const float4* ks = (const float4*)(K + src);
        const float4* vs = (const float4*)(V + src);
        #pragma unroll
        for (int t = 0; t < 8; ++t) {
            float4 kf = ks[t];
            unsigned int p0 = (unsigned int)f2bf(kf.x) | ((unsigned int)f2bf(kf.y) << 16);
            unsigned int p1 = (unsigned int)f2bf(kf.z) | ((unsigned int)f2bf(kf.w) << 16);
            *(unsigned int*)&Kc[j][h + 4 * t]     = p0;
            *(unsigned int*)&Kc[j][h + 4 * t + 2] = p1;
        }
        #pragma unroll
        for (int t = 0; t < 8; ++t) {
            float4 vf = vs[t];
            VcT[h + 4 * t + 0][j] = f2bf(vf.x);
            VcT[h + 4 * t + 1][j] = f2bf(vf.y);
            VcT[h + 4 * t + 2][j] = f2bf(vf.z);
            VcT[h + 4 * t + 3][j] = f2bf(vf.w);
        }
    }

    // ---- Q fragments (direct from global, pre-scaled by 1/8) ----
    const int kq = (lane >> 4) << 3;           // 8-dim group base
    short8 qa[2];
    {
        const int qrow = (wid << 4) + (lane & 15);
        const float* qp = Q + (rowbase + qrow) * EDIM;
        #pragma unroll
        for (int s = 0; s < 2; ++s) {
            float4 f0 = *(const float4*)(qp + 32 * s + kq);
            float4 f1 = *(const float4*)(qp + 32 * s + kq + 4);
            short8 v;
            v[0] = (short)f2bf(f0.x * 0.125f); v[1] = (short)f2bf(f0.y * 0.125f);
            v[2] = (short)f2bf(f0.z * 0.125f); v[3] = (short)f2bf(f0.w * 0.125f);
            v[4] = (short)f2bf(f1.x * 0.125f); v[5] = (short)f2bf(f1.y * 0.125f);
            v[6] = (short)f2bf(f1.z * 0.125f); v[7] = (short)f2bf(f1.w * 0.125f);
            qa[s] = v;
        }
    }
    __syncthreads();

    // ---- GEMM1: 8 col-tiles x 2 K-steps ----
    f32x4 acc[8];
    #pragma unroll
    for (int t = 0; t < 8; ++t) acc[t] = (f32x4)0.f;
    #pragma unroll
    for (int t = 0; t < 8; ++t) {
        const unsigned short* kr = &Kc[(t << 4) + (lane & 15)][0];
        short8 b0 = *(const short8*)(kr + kq);
        short8 b1 = *(const short8*)(kr + 32 + kq);
        acc[t] = __builtin_amdgcn_mfma_f32_16x16x32_bf16(qa[0], b0, acc[t], 0, 0, 0);
        acc[t] = __builtin_amdgcn_mfma_f32_16x16x32_bf16(qa[1], b1, acc[t], 0, 0, 0);
    }

    // ---- mask + exp + row sums (C layout: col=lane&15, row=(lane>>4)*4+reg) ----
    const int rb = (wid << 4) + ((lane >> 4) << 2);   // row of reg 0 (in 64-block)
    float rinv[4];
    #pragma unroll
    for (int reg = 0; reg < 4; ++reg) {
        const int r  = rb + reg;
        const int nv = m + (r == 63 ? 1 : 0);
        float sum = 0.f;
        #pragma unroll
        for (int t = 0; t < 8; ++t) {
            const int jc = (t << 4) + (lane & 15);
            float e = (jc < nv) ? __expf(acc[t][reg]) : 0.f;
            acc[t][reg] = e;
            sum += e;
        }
        sum += __shfl_xor(sum, 1); sum += __shfl_xor(sum, 2);
        sum += __shfl_xor(sum, 4); sum += __shfl_xor(sum, 8);
        rinv[reg] = (sum > 0.f) ? 1.0f / sum : 0.f;
    }

    // ---- normalized weights -> LDS (bf16) ----
    #pragma unroll
    for (int reg = 0; reg < 4; ++reg) {
        #pragma unroll
        for (int t = 0; t < 8; ++t)
            Aw[rb + reg][(t << 4) + (lane & 15)] = f2bf(acc[t][reg] * rinv[reg]);
    }
    __syncthreads();

    // ---- A output: coalesced f32 from Aw ----
    {
        const int row = tid >> 2;
        const int c0  = (tid & 3) << 5;            // 0,32,64,96
        const unsigned short* src = &Aw[row][c0];
        float4* dst = (float4*)(A + (rowbase + row) * NCOL + c0);
        #pragma unroll
        for (int g = 0; g < 4; ++g) {
            short8 u = *(const short8*)(src + 8 * g);
            float4 lo, hi;
            lo.x = bf2f((unsigned short)u[0]); lo.y = bf2f((unsigned short)u[1]);
            lo.z = bf2f((unsigned short)u[2]); lo.w = bf2f((unsigned short)u[3]);
            hi.x = bf2f((unsigned short)u[4]); hi.y = bf2f((unsigned short)u[5]);
            hi.z = bf2f((unsigned short)u[6]); hi.w = bf2f((unsigned short)u[7]);
            dst[2 * g] = lo; dst[2 * g + 1] = hi;
        }
    }

    // ---- GEMM2: out(64x64) = Aw(64x128) . Vc(128x64); 4 tiles x 4 K-steps ----
    short8 af[4];
    {
        const unsigned short* ar = &Aw[(wid << 4) + (lane & 15)][0];
        #pragma unroll
        for (int s = 0; s < 4; ++s) af[s] = *(const short8*)(ar + (s << 5) + kq);
    }
    f32x4 oacc[4];
    #pragma unroll
    for (int t = 0; t < 4; ++t) oacc[t] = (f32x4)0.f;
    #pragma unroll
    for (int t = 0; t < 4; ++t) {
        const unsigned short* vr = &VcT[(t << 4) + (lane & 15)][0];
        #pragma unroll
        for (int s = 0; s < 4; ++s) {
            short8 vb = *(const short8*)(vr + (s << 5) + kq);
            oacc[t] = __builtin_amdgcn_mfma_f32_16x16x32_bf16(af[s], vb, oacc[t], 0, 0, 0);
        }
    }
    #pragma unroll
    for (int t = 0; t < 4; ++t) {
        #pragma unroll
        for (int reg = 0; reg < 4; ++reg) {
            Out[(rowbase + rb + reg) * EDIM + (t << 4) + (lane & 15)] = oacc[t][reg];
        }
    }
}

extern "C" void kernel_launch(void* const* d_in, const int* in_sizes, int n_in,
                              void* d_out, int out_size, void* d_ws, size_t ws_size,
                              hipStream_t stream) {
    const float* Q = (const float*)d_in[0];
    const float* K = (const float*)d_in[1];
    const float* V = (const float*)d_in[2];
    float* Out = (float*)d_out;
    float* A   = Out + (size_t)NBATCH * TSEQ * EDIM;

    // 2048 workgroups x 256 threads: one per (batch, row-block)
    cba_kernel<<<dim3(NBATCH * NCOL), dim3(256), 0, stream>>>(Q, K, V, Out, A);
}